// Round 14
// baseline (135.169 us; speedup 1.0000x reference)
//
#include <hip/hip_runtime.h>
#include <math.h>
#include <stdint.h>

#define NCLS 128
constexpr float ALPHA = 0.5f;
constexpr float BETA_ = 0.5f;
constexpr float EPS_ = 1e-9f;

// ws: gL[128] double | gce double | gcnt[128] uint = 1544 B ; probe sink at +4096
__global__ void zero_ws(uint32_t* __restrict__ ws) {
    const int t = threadIdx.x;               // 256 threads, 386 words
    if (t < 386) ws[t] = 0u;
    if (t + 256 < 386) ws[t + 256] = 0u;
}

// ===== round-11 champion, unchanged (60.6 us) =====
__global__ __launch_bounds__(256, 6) void loss_main(
    const float* __restrict__ y_pred,
    const int*   __restrict__ y_true,
    double* __restrict__ gL, unsigned int* __restrict__ gcnt,
    double* __restrict__ gce, int nrows)
{
    __shared__ float    sL[NCLS];
    __shared__ unsigned scnt[NCLS];
    __shared__ float    sce;

    const int t = threadIdx.x;
    if (t == 0) sce = 0.f;
    if (t < NCLS) { sL[t] = 0.f; scnt[t] = 0u; }
    __syncthreads();

    const int lane = t & 63;
    const int half = lane >> 5;
    const int l32  = lane & 31;
    const int wgl  = blockIdx.x * (blockDim.x >> 6) + (t >> 6);
    const int nW   = gridDim.x * (blockDim.x >> 6);
    const int nPairs = nrows >> 1;

    float ce_local = 0.f;

    int p0 = wgl * 8;
    for (; p0 + 7 < nPairs; p0 += nW * 8) {
        float4 v[8]; int lab[8];
        const float* base = y_pred + ((size_t)(p0 << 1) + half) * NCLS + (l32 << 2);
        #pragma unroll
        for (int u = 0; u < 8; ++u) {
            v[u]   = *reinterpret_cast<const float4*>(base + (size_t)(u << 1) * NCLS);
            lab[u] = y_true[((p0 + u) << 1) + half];
        }
        float S[8];
        #pragma unroll
        for (int u = 0; u < 8; ++u) {
            const float ex = __expf(v[u].x), ey = __expf(v[u].y);
            const float ez = __expf(v[u].z), ew = __expf(v[u].w);
            S[u] = (ex + ey) + (ez + ew);
        }
        #pragma unroll
        for (int off = 16; off; off >>= 1) {
            #pragma unroll
            for (int u = 0; u < 8; ++u) S[u] += __shfl_xor(S[u], off);
        }
        float tv[8];
        #pragma unroll
        for (int u = 0; u < 8; ++u) {
            const int ls = lab[u] & 3;
            const float vsel = (ls == 0) ? v[u].x : (ls == 1) ? v[u].y
                             : (ls == 2) ? v[u].z : v[u].w;
            tv[u] = __shfl(vsel, (half << 5) + (lab[u] >> 2));
        }
        if (l32 == 0) {
            #pragma unroll
            for (int u = 0; u < 8; ++u) {
                ce_local += tv[u] - __logf(S[u]);
                const float p1 = __expf(v[u].x) / S[u];
                const float contrib = (lab[u] == 0) ? ALPHA * __logf(p1 + EPS_)
                                                    : __logf(1.f - p1 + EPS_);
                atomicAdd(&sL[lab[u]], contrib);
                atomicAdd(&scnt[lab[u]], 1u);
            }
        }
    }
    for (; p0 < nPairs; ++p0) {
        const int row = (p0 << 1) + half;
        const float4 v = *reinterpret_cast<const float4*>(
            y_pred + (size_t)row * NCLS + (l32 << 2));
        const int lab = y_true[row];
        const float ex = __expf(v.x), ey = __expf(v.y);
        const float ez = __expf(v.z), ew = __expf(v.w);
        float S = (ex + ey) + (ez + ew);
        #pragma unroll
        for (int off = 16; off; off >>= 1) S += __shfl_xor(S, off);
        const int ls = lab & 3;
        const float vsel = (ls == 0) ? v.x : (ls == 1) ? v.y : (ls == 2) ? v.z : v.w;
        const float tv = __shfl(vsel, (half << 5) + (lab >> 2));
        if (l32 == 0) {
            ce_local += tv - __logf(S);
            const float p1 = ex / S;
            const float contrib = (lab == 0) ? ALPHA * __logf(p1 + EPS_)
                                             : __logf(1.f - p1 + EPS_);
            atomicAdd(&sL[lab], contrib);
            atomicAdd(&scnt[lab], 1u);
        }
    }
    if (nrows & 1) {
        if (wgl == 0) {
            const int row = nrows - 1;
            const float4 v = *reinterpret_cast<const float4*>(
                y_pred + (size_t)row * NCLS + (l32 << 2));
            const int lab = y_true[row];
            const float ex = __expf(v.x), ey = __expf(v.y);
            const float ez = __expf(v.z), ew = __expf(v.w);
            float S = (ex + ey) + (ez + ew);
            #pragma unroll
            for (int off = 16; off; off >>= 1) S += __shfl_xor(S, off);
            const int ls = lab & 3;
            const float vsel = (ls == 0) ? v.x : (ls == 1) ? v.y : (ls == 2) ? v.z : v.w;
            const float tv = __shfl(vsel, (half << 5) + (lab >> 2));
            if (lane == 0) {
                ce_local += tv - __logf(S);
                const float p1 = ex / S;
                const float contrib = (lab == 0) ? ALPHA * __logf(p1 + EPS_)
                                                 : __logf(1.f - p1 + EPS_);
                atomicAdd(&sL[lab], contrib);
                atomicAdd(&scnt[lab], 1u);
            }
        }
    }

    float lp = ce_local;
    #pragma unroll
    for (int off = 32; off; off >>= 1) lp += __shfl_xor(lp, off);
    if (lane == 0) atomicAdd(&sce, lp);
    __syncthreads();

    if (t < NCLS) {
        if (scnt[t]) {
            atomicAdd(&gL[t], (double)sL[t]);
            atomicAdd(&gcnt[t], scnt[t]);
        }
    }
    if (t == 0) atomicAdd(gce, (double)sce);
}

__global__ void loss_final(const double* __restrict__ gL,
                           const unsigned int* __restrict__ gcnt,
                           const double* __restrict__ gce,
                           float* __restrict__ out, int nrows)
{
    const int lane = threadIdx.x;   // 64 threads
    const double denom = (double)nrows - (double)gcnt[0];
    double local = 0.0;
    for (int c = lane; c < NCLS; c += 64) {
        if (c == 0) local += gL[0];
        else        local += (double)BETA_ * (1.0 - (double)gcnt[c] / denom) * gL[c];
    }
    #pragma unroll
    for (int off = 32; off; off >>= 1) local += __shfl_down(local, off);
    if (lane == 0) {
        const double ce = -gce[0] / (double)nrows;
        out[0] = (float)(ce - local / (double)nrows);
    }
}

// ===== DIAGNOSTIC PROBE: loss_main's exact load pattern, compute stripped =====
// Same grid (1024x256), same wave->pair mapping, same 8x1KB batched float4 loads
// + label loads; 4 passes over the input (~516 MB delivered) so it lands in the
// profiler top-5 with its own FETCH_SIZE / hbm_gbps. All 4 components consumed
// (3 adds per float4) so loads can't be narrowed or DCE'd. Sink -> ws scratch.
__global__ __launch_bounds__(256, 6) void probe_stream(
    const float* __restrict__ y_pred,
    const int*   __restrict__ y_true,
    float* __restrict__ sink, int nrows)
{
    const int t = threadIdx.x;
    const int lane = t & 63;
    const int half = lane >> 5;
    const int l32  = lane & 31;
    const int wgl  = blockIdx.x * (blockDim.x >> 6) + (t >> 6);
    const int nW   = gridDim.x * (blockDim.x >> 6);
    const int nPairs = nrows >> 1;

    float acc = 0.f;
    for (int pass = 0; pass < 4; ++pass) {
        for (int p0 = wgl * 8; p0 + 7 < nPairs; p0 += nW * 8) {
            float4 v[8]; int lab[8];
            const float* base = y_pred + ((size_t)(p0 << 1) + half) * NCLS + (l32 << 2);
            #pragma unroll
            for (int u = 0; u < 8; ++u) {
                v[u]   = *reinterpret_cast<const float4*>(base + (size_t)(u << 1) * NCLS);
                lab[u] = y_true[((p0 + u) << 1) + half];
            }
            #pragma unroll
            for (int u = 0; u < 8; ++u)
                acc += (v[u].x + v[u].y) + (v[u].z + v[u].w) + (float)lab[u];
        }
    }
    sink[(size_t)wgl * 64 + lane] = acc;
}

extern "C" void kernel_launch(void* const* d_in, const int* in_sizes, int n_in,
                              void* d_out, int out_size, void* d_ws, size_t ws_size,
                              hipStream_t stream) {
    const float* y_pred = (const float*)d_in[0];
    const int*   y_true = (const int*)d_in[1];
    const int nrows = in_sizes[1];

    double*   gL   = (double*)d_ws;                        // 1024 B
    double*   gce  = (double*)((char*)d_ws + 1024);        // 8 B
    unsigned* gcnt = (unsigned*)((char*)d_ws + 1032);      // 512 B
    float*    sink = (float*)((char*)d_ws + 4096);         // 1 MB probe scratch

    zero_ws<<<dim3(1), dim3(256), 0, stream>>>((uint32_t*)d_ws);

    loss_main<<<dim3(1024), dim3(256), 0, stream>>>(y_pred, y_true, gL, gcnt, gce, nrows);
    loss_final<<<dim3(1), dim3(64), 0, stream>>>(gL, gcnt, gce, (float*)d_out, nrows);

    // diagnostic probe (sacrificial round): measures achievable BW of the exact
    // access pattern, visible in rocprof top-5.
    probe_stream<<<dim3(1024), dim3(256), 0, stream>>>(y_pred, y_true, sink, nrows);
}

// Round 15
// 40.529 us; speedup vs baseline: 3.3351x; 3.3351x over previous
//
#include <hip/hip_runtime.h>
#include <math.h>
#include <stdint.h>

#define NCLS 128
#define NBANK 8
constexpr float ALPHA = 0.5f;
constexpr float BETA_ = 0.5f;
constexpr float EPS_ = 1e-9f;

// ws: gLb[128][8] double (8192 B) | gceb[8] double (64 B) | gcntb[128][8] uint (4096 B)
__global__ void zero_ws(uint32_t* __restrict__ ws) {
    const int t = threadIdx.x;               // 256 threads, 3088 words
    for (int i = t; i < 3088; i += 256) ws[i] = 0u;
}

// Round-11 champion computation, reshaped 256 blocks x 1024 threads (same 4096
// waves, same wave->pair mapping) + 8 shadow banks per class: global atomic
// chains drop from 1024-deep on 128 addresses to 32-deep on 1024 addresses.
// (R14 probe proved the load pattern alone sustains 6.8 TB/s / ~20 us per pass;
// the serialized f64-atomic tail is the prime suspect for the remaining gap.)
__global__ __launch_bounds__(1024, 4) void loss_main(
    const float* __restrict__ y_pred,
    const int*   __restrict__ y_true,
    double* __restrict__ gLb, unsigned int* __restrict__ gcntb,
    double* __restrict__ gceb, int nrows)
{
    __shared__ float    sL[NCLS];
    __shared__ unsigned scnt[NCLS];
    __shared__ float    sce;

    const int t = threadIdx.x;
    if (t == 0) sce = 0.f;
    if (t < NCLS) { sL[t] = 0.f; scnt[t] = 0u; }
    __syncthreads();

    const int lane = t & 63;
    const int half = lane >> 5;
    const int l32  = lane & 31;
    const int wgl  = blockIdx.x * (blockDim.x >> 6) + (t >> 6);   // 0..4095
    const int nW   = gridDim.x * (blockDim.x >> 6);               // 4096
    const int nPairs = nrows >> 1;

    float ce_local = 0.f;

    int p0 = wgl * 8;
    for (; p0 + 7 < nPairs; p0 += nW * 8) {
        float4 v[8]; int lab[8];
        const float* base = y_pred + ((size_t)(p0 << 1) + half) * NCLS + (l32 << 2);
        #pragma unroll
        for (int u = 0; u < 8; ++u) {
            v[u]   = *reinterpret_cast<const float4*>(base + (size_t)(u << 1) * NCLS);
            lab[u] = y_true[((p0 + u) << 1) + half];
        }
        float S[8];
        #pragma unroll
        for (int u = 0; u < 8; ++u) {
            const float ex = __expf(v[u].x), ey = __expf(v[u].y);
            const float ez = __expf(v[u].z), ew = __expf(v[u].w);
            S[u] = (ex + ey) + (ez + ew);
        }
        #pragma unroll
        for (int off = 16; off; off >>= 1) {
            #pragma unroll
            for (int u = 0; u < 8; ++u) S[u] += __shfl_xor(S[u], off);
        }
        float tv[8];
        #pragma unroll
        for (int u = 0; u < 8; ++u) {
            const int ls = lab[u] & 3;
            const float vsel = (ls == 0) ? v[u].x : (ls == 1) ? v[u].y
                             : (ls == 2) ? v[u].z : v[u].w;
            tv[u] = __shfl(vsel, (half << 5) + (lab[u] >> 2));
        }
        if (l32 == 0) {
            #pragma unroll
            for (int u = 0; u < 8; ++u) {
                ce_local += tv[u] - __logf(S[u]);
                const float p1 = __expf(v[u].x) / S[u];
                const float contrib = (lab[u] == 0) ? ALPHA * __logf(p1 + EPS_)
                                                    : __logf(1.f - p1 + EPS_);
                atomicAdd(&sL[lab[u]], contrib);
                atomicAdd(&scnt[lab[u]], 1u);
            }
        }
    }
    for (; p0 < nPairs; ++p0) {
        const int row = (p0 << 1) + half;
        const float4 v = *reinterpret_cast<const float4*>(
            y_pred + (size_t)row * NCLS + (l32 << 2));
        const int lab = y_true[row];
        const float ex = __expf(v.x), ey = __expf(v.y);
        const float ez = __expf(v.z), ew = __expf(v.w);
        float S = (ex + ey) + (ez + ew);
        #pragma unroll
        for (int off = 16; off; off >>= 1) S += __shfl_xor(S, off);
        const int ls = lab & 3;
        const float vsel = (ls == 0) ? v.x : (ls == 1) ? v.y : (ls == 2) ? v.z : v.w;
        const float tv = __shfl(vsel, (half << 5) + (lab >> 2));
        if (l32 == 0) {
            ce_local += tv - __logf(S);
            const float p1 = ex / S;
            const float contrib = (lab == 0) ? ALPHA * __logf(p1 + EPS_)
                                             : __logf(1.f - p1 + EPS_);
            atomicAdd(&sL[lab], contrib);
            atomicAdd(&scnt[lab], 1u);
        }
    }
    if (nrows & 1) {
        if (wgl == 0) {
            const int row = nrows - 1;
            const float4 v = *reinterpret_cast<const float4*>(
                y_pred + (size_t)row * NCLS + (l32 << 2));
            const int lab = y_true[row];
            const float ex = __expf(v.x), ey = __expf(v.y);
            const float ez = __expf(v.z), ew = __expf(v.w);
            float S = (ex + ey) + (ez + ew);
            #pragma unroll
            for (int off = 16; off; off >>= 1) S += __shfl_xor(S, off);
            const int ls = lab & 3;
            const float vsel = (ls == 0) ? v.x : (ls == 1) ? v.y : (ls == 2) ? v.z : v.w;
            const float tv = __shfl(vsel, (half << 5) + (lab >> 2));
            if (lane == 0) {
                ce_local += tv - __logf(S);
                const float p1 = ex / S;
                const float contrib = (lab == 0) ? ALPHA * __logf(p1 + EPS_)
                                                 : __logf(1.f - p1 + EPS_);
                atomicAdd(&sL[lab], contrib);
                atomicAdd(&scnt[lab], 1u);
            }
        }
    }

    float lp = ce_local;
    #pragma unroll
    for (int off = 32; off; off >>= 1) lp += __shfl_xor(lp, off);
    if (lane == 0) atomicAdd(&sce, lp);
    __syncthreads();

    // flush: rotated class order, 8 shadow banks -> 32-deep chains per address
    const int bank = blockIdx.x & (NBANK - 1);
    if (t < NCLS) {
        const int c = (t + blockIdx.x) & (NCLS - 1);
        if (scnt[c]) {
            atomicAdd(&gLb[c * NBANK + bank], (double)sL[c]);
            atomicAdd(&gcntb[c * NBANK + bank], scnt[c]);
        }
    }
    if (t == 0) atomicAdd(&gceb[bank], (double)sce);
}

__global__ void loss_final(const double* __restrict__ gLb,
                           const unsigned int* __restrict__ gcntb,
                           const double* __restrict__ gceb,
                           float* __restrict__ out, int nrows)
{
    const int lane = threadIdx.x;   // 64 threads
    double cnt0 = 0.0;
    #pragma unroll
    for (int b = 0; b < NBANK; ++b) cnt0 += (double)gcntb[0 * NBANK + b];
    const double denom = (double)nrows - cnt0;

    double local = 0.0;
    for (int c = lane; c < NCLS; c += 64) {
        double Lc = 0.0, nc = 0.0;
        #pragma unroll
        for (int b = 0; b < NBANK; ++b) {
            Lc += gLb[c * NBANK + b];
            nc += (double)gcntb[c * NBANK + b];
        }
        if (c == 0) local += Lc;                          // ALPHA pre-applied
        else        local += (double)BETA_ * (1.0 - nc / denom) * Lc;
    }
    #pragma unroll
    for (int off = 32; off; off >>= 1) local += __shfl_down(local, off);
    if (lane == 0) {
        double ce = 0.0;
        #pragma unroll
        for (int b = 0; b < NBANK; ++b) ce += gceb[b];
        ce = -ce / (double)nrows;
        out[0] = (float)(ce - local / (double)nrows);
    }
}

extern "C" void kernel_launch(void* const* d_in, const int* in_sizes, int n_in,
                              void* d_out, int out_size, void* d_ws, size_t ws_size,
                              hipStream_t stream) {
    const float* y_pred = (const float*)d_in[0];
    const int*   y_true = (const int*)d_in[1];
    const int nrows = in_sizes[1];

    double*   gLb   = (double*)d_ws;                       // 8192 B
    double*   gceb  = (double*)((char*)d_ws + 8192);       // 64 B
    unsigned* gcntb = (unsigned*)((char*)d_ws + 8256);     // 4096 B

    zero_ws<<<dim3(1), dim3(256), 0, stream>>>((uint32_t*)d_ws);

    loss_main<<<dim3(256), dim3(1024), 0, stream>>>(y_pred, y_true, gLb, gcntb, gceb, nrows);
    loss_final<<<dim3(1), dim3(64), 0, stream>>>(gLb, gcntb, gceb, (float*)d_out, nrows);
}